// Round 11
// baseline (83.758 us; speedup 1.0000x reference)
//
#include <hip/hip_runtime.h>

// B=32, G=512
// out layout: [rel_pos (B,G,G,3) | rel_ori (B,G,G,3,3)] flat f32
//
// Persistent blocks + raw-barrier (lgkmcnt-only) loop:
//  - 2048 blocks (8/CU, all resident), 256 thr, 12 KB LDS
//  - block p owns rows 8p..8p+7 -> sequential 48 KB pos / 144 KB ori streams
//  - per half-row iteration: compute -> ds_write -> lgkmcnt(0)+s_barrier
//    -> float4 writeback -> lgkmcnt(0)+s_barrier
//  - NO vmcnt drain anywhere in the loop (unlike __syncthreads): global
//    stores stay in flight across barriers, exactly the AITER counted-vmcnt
//    principle. Stores retire after s_endpgm.

#define G_ 512
#define NB 32

typedef float f4v __attribute__((ext_vector_type(4)));

__global__ __launch_bounds__(256, 8) void relposori_kernel(
    const float* __restrict__ center,   // (B,G,6)
    const float* __restrict__ lrf,      // (B,G,3,3)
    float* __restrict__ out_pos,        // (B,G,G,3)
    float* __restrict__ out_ori)        // (B,G,G,3,3)
{
    __shared__ float s[3072];           // 12 KB: [0,768) pos | [768,3072) ori
    float* s_pos = s;
    float* s_ori = s + 768;

    int tid = threadIdx.x;
    int p   = blockIdx.x;               // 0..2047
    int bi0 = p << 3;                   // first of 8 consecutive rows
    int b   = bi0 >> 9;                 // block-uniform (512 % 8 == 0)

    const float* cb = center + (size_t)b * (G_ * 6);
    const float* lb = lrf    + (size_t)b * (G_ * 9);

    for (int rr = 0; rr < 8; ++rr) {
        int bi = bi0 + rr;

        // row-uniform inputs (scalar loads)
        const float* ci = center + (size_t)bi * 6;
        const float* li = lrf    + (size_t)bi * 9;
        float ci0 = ci[0], ci1 = ci[1], ci2 = ci[2];
        float li_[9];
#pragma unroll
        for (int t = 0; t < 9; ++t) li_[t] = li[t];

#pragma unroll
        for (int half = 0; half < 2; ++half) {
            int j = (half << 8) | tid;
            const float* cj = cb + j * 6;   // same addrs every rr -> L1 hits
            const float* lj = lb + j * 9;
            float d0 = cj[0] - ci0, d1 = cj[1] - ci1, d2 = cj[2] - ci2;
            float lj_[9];
#pragma unroll
            for (int t = 0; t < 9; ++t) lj_[t] = lj[t];

            // rel_pos[k] = sum_c d[c] * lrf_i[c][k]
#pragma unroll
            for (int k = 0; k < 3; ++k)
                s_pos[tid * 3 + k] = d0 * li_[k] + d1 * li_[3 + k] + d2 * li_[6 + k];

            // rel_ori[m][n] = sum_k lrf_i[k][m] * lrf_j[k][n]
#pragma unroll
            for (int m = 0; m < 3; ++m)
#pragma unroll
                for (int n = 0; n < 3; ++n)
                    s_ori[tid * 9 + m * 3 + n] = li_[m]     * lj_[n]
                                               + li_[3 + m] * lj_[3 + n]
                                               + li_[6 + m] * lj_[6 + n];

            // RAW barrier: LDS writes visible to all waves. lgkm only --
            // in-flight global stores are NOT drained (vs __syncthreads).
            asm volatile("s_waitcnt lgkmcnt(0)" ::: "memory");
            __builtin_amdgcn_s_barrier();

            // Fused float4 writeback: 768 f4 = 3 per thread; t<192 split is
            // at a wave boundary (no intra-wave divergence).
            const f4v* s4 = (const f4v*)s;
            f4v* op4 = (f4v*)out_pos + ((size_t)bi * 384  + (size_t)half * 192);
            f4v* oo4 = (f4v*)out_ori + ((size_t)bi * 1152 + (size_t)half * 576);
#pragma unroll
            for (int it = 0; it < 3; ++it) {
                int t = tid + (it << 8);
                if (t < 192) op4[t]       = s4[t];
                else         oo4[t - 192] = s4[t];
            }

            // WAR barrier: all waves' ds_reads done (each wave's reads
            // completed before its dependent stores issued; lgkmcnt(0)
            // re-asserts) before next iteration overwrites the slice.
            asm volatile("s_waitcnt lgkmcnt(0)" ::: "memory");
            __builtin_amdgcn_s_barrier();
        }
    }
}

extern "C" void kernel_launch(void* const* d_in, const int* in_sizes, int n_in,
                              void* d_out, int out_size, void* d_ws, size_t ws_size,
                              hipStream_t stream) {
    const float* center = (const float*)d_in[0];
    const float* lrf    = (const float*)d_in[1];
    float* out = (float*)d_out;

    const int B = 32;
    const size_t n_pos = (size_t)B * G_ * G_ * 3;   // 25,165,824 floats
    float* out_pos = out;
    float* out_ori = out + n_pos;

    dim3 grid(2048);    // 8 rows per block, zero tail, all resident
    dim3 block(256);
    hipLaunchKernelGGL(relposori_kernel, grid, block, 0, stream,
                       center, lrf, out_pos, out_ori);
}

// Round 12
// 78.497 us; speedup vs baseline: 1.0670x; 1.0670x over previous
//
#include <hip/hip_runtime.h>

// B=32, G=512
// out layout: [rel_pos (B,G,G,3) | rel_ori (B,G,G,3,3)] flat f32
//
// One-shot FULL-ROW block, two half-row phases, prefetch-above-stores:
//  - 16384 blocks, 256 thr, 12 KB LDS (single half-row buffer) -> 8 blocks/CU
//  - phase structure per block:
//      load(h0) -> compute/ds_write(h0) -> __syncthreads (vmcnt==0, free)
//      -> PREFETCH load(h1)            // loads enter vmem queue BEFORE stores
//      -> writeback stores(h0)
//      -> raw s_barrier                 // WAR on LDS; stores NOT drained
//      -> compute/ds_write(h1)          // vmcnt waits only for the loads
//      -> lgkmcnt(0)+s_barrier -> writeback(h1) -> endpgm
//  - stores never wait in-block; loads never queue behind stores.

#define G_ 512

typedef float f4v __attribute__((ext_vector_type(4)));
typedef float f4u __attribute__((ext_vector_type(4), aligned(4)));

__global__ __launch_bounds__(256, 8) void relposori_kernel(
    const float* __restrict__ center,   // (B,G,6)
    const float* __restrict__ lrf,      // (B,G,3,3)
    float* __restrict__ out_pos,        // (B,G,G,3)
    float* __restrict__ out_ori)        // (B,G,G,3,3)
{
    __shared__ float s[3072];           // 12 KB: [0,768) pos | [768,3072) ori
    float* s_pos = s;
    float* s_ori = s + 768;

    int bi  = blockIdx.x;               // one full row per block
    int b   = bi >> 9;
    int tid = threadIdx.x;

    const float* cb = center + (size_t)b * (G_ * 6);
    const float* lb = lrf    + (size_t)b * (G_ * 9);

    // row-uniform inputs (scalar loads)
    const float* ci = center + (size_t)bi * 6;
    const float* li = lrf    + (size_t)bi * 9;
    float ci0 = ci[0], ci1 = ci[1], ci2 = ci[2];
    float li_[9];
#pragma unroll
    for (int t = 0; t < 9; ++t) li_[t] = li[t];

    // ---- half-0 input loads (fresh wave context: nothing queued) ----
    const float* cj0 = cb + tid * 6;
    const float* lj0 = lb + tid * 9;
    f4u c03 = *(const f4u*)cj0;          // cj[0..3] ([3] unused, in-row)
    f4u l03 = *(const f4u*)lj0;
    f4u l47 = *(const f4u*)(lj0 + 4);
    float l8 = lj0[8];

    // ---- half-0 compute -> LDS ----
    {
        float d0 = c03.x - ci0, d1 = c03.y - ci1, d2 = c03.z - ci2;
        float lj_[9] = { l03.x, l03.y, l03.z, l03.w,
                         l47.x, l47.y, l47.z, l47.w, l8 };
#pragma unroll
        for (int k = 0; k < 3; ++k)
            s_pos[tid * 3 + k] = d0 * li_[k] + d1 * li_[3 + k] + d2 * li_[6 + k];
#pragma unroll
        for (int m = 0; m < 3; ++m)
#pragma unroll
            for (int n = 0; n < 3; ++n)
                s_ori[tid * 9 + m * 3 + n] = li_[m]     * lj_[n]
                                           + li_[3 + m] * lj_[3 + n]
                                           + li_[6 + m] * lj_[6 + n];
    }
    __syncthreads();   // vmcnt already 0 (loads consumed) -> cheap

    // ---- PREFETCH half-1 inputs: issued BEFORE the half-0 store burst ----
    const float* cj1 = cb + (256 + tid) * 6;
    const float* lj1 = lb + (256 + tid) * 9;
    f4u c03b = *(const f4u*)cj1;
    f4u l03b = *(const f4u*)lj1;
    f4u l47b = *(const f4u*)(lj1 + 4);
    float l8b = lj1[8];
    asm volatile("" ::: "memory");       // pin: loads above, writeback below

    // ---- half-0 writeback: 3 float4 stores/thread (wave-aligned split) ----
    {
        const f4v* s4 = (const f4v*)s;
        f4v* op4 = (f4v*)out_pos + (size_t)bi * 384;
        f4v* oo4 = (f4v*)out_ori + (size_t)bi * 1152;
#pragma unroll
        for (int it = 0; it < 3; ++it) {
            int t = tid + (it << 8);
            if (t < 192) op4[t]       = s4[t];
            else         oo4[t - 192] = s4[t];
        }
    }

    // WAR barrier: every wave arriving here has consumed its ds_reads
    // (stores depend on them). Raw s_barrier -> stores stay in flight.
    asm volatile("" ::: "memory");
    __builtin_amdgcn_s_barrier();

    // ---- half-1 compute -> LDS (vmcnt wait covers only the prefetch) ----
    {
        float d0 = c03b.x - ci0, d1 = c03b.y - ci1, d2 = c03b.z - ci2;
        float lj_[9] = { l03b.x, l03b.y, l03b.z, l03b.w,
                         l47b.x, l47b.y, l47b.z, l47b.w, l8b };
#pragma unroll
        for (int k = 0; k < 3; ++k)
            s_pos[tid * 3 + k] = d0 * li_[k] + d1 * li_[3 + k] + d2 * li_[6 + k];
#pragma unroll
        for (int m = 0; m < 3; ++m)
#pragma unroll
            for (int n = 0; n < 3; ++n)
                s_ori[tid * 9 + m * 3 + n] = li_[m]     * lj_[n]
                                           + li_[3 + m] * lj_[3 + n]
                                           + li_[6 + m] * lj_[6 + n];
    }
    // RAW barrier, LDS only: in-flight global stores NOT drained.
    asm volatile("s_waitcnt lgkmcnt(0)" ::: "memory");
    __builtin_amdgcn_s_barrier();

    // ---- half-1 writeback, then block ends (stores drain after endpgm) ----
    {
        const f4v* s4 = (const f4v*)s;
        f4v* op4 = (f4v*)out_pos + (size_t)bi * 384  + 192;
        f4v* oo4 = (f4v*)out_ori + (size_t)bi * 1152 + 576;
#pragma unroll
        for (int it = 0; it < 3; ++it) {
            int t = tid + (it << 8);
            if (t < 192) op4[t]       = s4[t];
            else         oo4[t - 192] = s4[t];
        }
    }
}

extern "C" void kernel_launch(void* const* d_in, const int* in_sizes, int n_in,
                              void* d_out, int out_size, void* d_ws, size_t ws_size,
                              hipStream_t stream) {
    const float* center = (const float*)d_in[0];
    const float* lrf    = (const float*)d_in[1];
    float* out = (float*)d_out;

    const int B = 32;
    const size_t n_pos = (size_t)B * G_ * G_ * 3;   // 25,165,824 floats
    float* out_pos = out;
    float* out_ori = out + n_pos;

    dim3 grid(B * G_);   // 16384 one-shot full-row blocks
    dim3 block(256);
    hipLaunchKernelGGL(relposori_kernel, grid, block, 0, stream,
                       center, lrf, out_pos, out_ori);
}